// Round 2
// baseline (730.144 us; speedup 1.0000x reference)
//
#include <hip/hip_runtime.h>

// GraphSAGEConv: out_i = mean_{j in N(i)} x_j @ W_l + b_l + x_i @ W_r
// N=100000, E=1600000, D_in=D_out=64.
//
// 5 dispatches:
//   memset:  bcnt/bfill (tiny)
//   prep:    convert x->bf16 xh, Wl/Wr->bf16  +  fine bucket histogram
//            (64-node buckets; 128 hist blocks, LDS hist, flush via atomics)
//   bscan:   1-block (1024 thr) pair-scan -> bbase[]
//   binpass: group edges by fine bucket, packed (src<<6)|(dst&63), written
//            line-dense into bucket regions of binned (256 blocks x 1024 thr)
//   sage_fused: one 256-thr block per 64 nodes:
//            - edge-parallel aggregation: each half-wave streams edges,
//              gathers the 128B bf16 row (dword/lane) and accumulates via
//              ds_add_f32 into per-node f32 sums in LDS ([64][33] layout:
//              bank-conflict-free).  No sort, no per-node serial chain, no
//              dependent drain -> loads stay in flight continuously.
//            - means = sums * 1/deg, packed bf16 into LDS (72-short pitch)
//            - dual-GEMM epilogue via mfma_f32_16x16x32_bf16 (K=128 fused)

#define DFEAT 64
#define NF2 2048                     // fine-bucket array size (N <= 131072)
#define MLD 72                       // means row pitch in shorts (bank-safe)

typedef short bf16x8 __attribute__((ext_vector_type(8)));
typedef float f32x4 __attribute__((ext_vector_type(4)));

static __device__ __forceinline__ unsigned short f2bf(float f) {
    unsigned int u = __float_as_uint(f);
    unsigned int r = (u + 0x7FFFu + ((u >> 16) & 1u)) >> 16;   // RNE
    return (unsigned short)r;
}
static __device__ __forceinline__ float bf2f_lo(unsigned int u) {
    return __uint_as_float(u << 16);
}
static __device__ __forceinline__ float bf2f_hi(unsigned int u) {
    return __uint_as_float(u & 0xFFFF0000u);
}

// convert (blocks [0, convBlocks)) + fine histogram (blocks [convBlocks, +128))
__launch_bounds__(256)
__global__ void prep(const float* __restrict__ x,
                     const float* __restrict__ Wl,
                     const float* __restrict__ Wr,
                     const int* __restrict__ dst,
                     unsigned short* __restrict__ xh,
                     unsigned short* __restrict__ wl16,
                     unsigned short* __restrict__ wr16,
                     int* __restrict__ bcnt,
                     int nx4, int convBlocks, int E, int nf) {
    __shared__ int h[NF2];
    int b = blockIdx.x, t = threadIdx.x;
    if (b < convBlocks) {
        int i = b * 256 + t;
        const float* sp; unsigned short* dp; int k;
        if (i < 1024)      { sp = Wl; dp = wl16; k = i; }
        else if (i < 2048) { sp = Wr; dp = wr16; k = i - 1024; }
        else if (i - 2048 < nx4) { sp = x; dp = xh; k = i - 2048; }
        else return;
        float4 v = ((const float4*)sp)[k];
        ushort4 hh;
        hh.x = f2bf(v.x); hh.y = f2bf(v.y); hh.z = f2bf(v.z); hh.w = f2bf(v.w);
        ((ushort4*)dp)[k] = hh;
        return;
    }
    int hb = b - convBlocks;                    // 0..127
    for (int i = t; i < nf; i += 256) h[i] = 0;
    __syncthreads();
    int chunk = (E + 127) / 128;
    int lo = hb * chunk;
    int hi = lo + chunk; if (hi > E) hi = E;
    for (int i = lo + t; i < hi; i += 256)
        atomicAdd(&h[((unsigned)dst[i]) >> 6], 1);
    __syncthreads();
    for (int i = t; i < nf; i += 256)
        if (h[i]) atomicAdd(&bcnt[i], h[i]);
}

// One-block exclusive scan of fine-bucket counts -> bbase[0..nf].
// 1024 threads, 2 elements each (nf <= 2048).
__global__ void bscan(const int* __restrict__ bcnt, int* __restrict__ bbase,
                      int nf) {
    __shared__ int a[2][1024];
    int t = threadIdx.x;                        // blockDim = 1024
    int c0 = (2 * t     < nf) ? bcnt[2 * t]     : 0;
    int c1 = (2 * t + 1 < nf) ? bcnt[2 * t + 1] : 0;
    a[0][t] = c0 + c1;
    __syncthreads();
    int cur = 0;
    for (int o = 1; o < 1024; o <<= 1) {
        a[cur ^ 1][t] = a[cur][t] + ((t >= o) ? a[cur][t - o] : 0);
        cur ^= 1;
        __syncthreads();
    }
    int base = (t == 0) ? 0 : a[cur][t - 1];    // exclusive pair-scan
    if (2 * t     < nf) bbase[2 * t]     = base;
    if (2 * t + 1 < nf) bbase[2 * t + 1] = base + c0;
    if (t == 1023) bbase[nf] = a[cur][1023];
}

// Group edges by fine bucket; write packed (src<<6 | dst&63) line-dense.
__launch_bounds__(1024)
__global__ void binpass(const int* __restrict__ src, const int* __restrict__ dst,
                        const int* __restrict__ bbase, int* __restrict__ bfill,
                        unsigned int* __restrict__ binned, int E, int nf) {
    __shared__ int hcnt[NF2];
    __shared__ int hbase[NF2];
    int t = threadIdx.x;
    int chunk = (E + 255) / 256;
    int lo = blockIdx.x * chunk;
    int hi = lo + chunk; if (hi > E) hi = E;

    for (int i = t; i < nf; i += 1024) hcnt[i] = 0;
    __syncthreads();
    for (int i = lo + t; i < hi; i += 1024)
        atomicAdd(&hcnt[((unsigned)dst[i]) >> 6], 1);
    __syncthreads();
    for (int i = t; i < nf; i += 1024) {
        int c = hcnt[i];
        hbase[i] = c > 0 ? (bbase[i] + atomicAdd(&bfill[i], c)) : 0;
        hcnt[i] = 0;
    }
    __syncthreads();
    for (int i = lo + t; i < hi; i += 1024) {
        int d = dst[i];
        int bu = ((unsigned)d) >> 6;
        int p = hbase[bu] + atomicAdd(&hcnt[bu], 1);
        binned[p] = (((unsigned)src[i]) << 6) | ((unsigned)d & 63u);
    }
}

// Fused edge-parallel aggregate + dual-GEMM. One 256-thr block per 64 nodes.
__launch_bounds__(256)
__global__ void sage_fused(const unsigned short* __restrict__ xh,
                           const unsigned int* __restrict__ binned,
                           const int* __restrict__ bbase,
                           const unsigned short* __restrict__ wl16,
                           const unsigned short* __restrict__ wr16,
                           const float* __restrict__ bl,
                           float* __restrict__ out, int N) {
    // sums: [even/odd][node][lane] with +1-pad pitch 33 -> atomics hit
    // 32 distinct banks per half-wave.  means (bf16, 72-short pitch)
    // reuses the same LDS after a reg-staged read + barrier.
    __shared__ union {
        float s[2][64][33];              // 16896 B
        unsigned short m[64 * MLD];      //  9216 B
    } u;
    __shared__ int scnt[64];

    int fb = blockIdx.x;
    int n0 = fb << 6;
    if (n0 >= N) return;
    int t = threadIdx.x;

    for (int i = t; i < 2 * 64 * 33; i += 256) ((float*)u.s)[i] = 0.f;
    if (t < 64) scnt[t] = 0;
    __syncthreads();

    int elo = bbase[fb], ehi = bbase[fb + 1];
    int h8 = t >> 5;                 // half-wave id 0..7
    int l2 = t & 31;

    // ---- edge-parallel gather + LDS-atomic accumulate (8-deep ILP) ----
    int i = elo + h8;
    for (; i + 56 < ehi; i += 64) {
        unsigned v[8]; unsigned r[8];
        #pragma unroll
        for (int q = 0; q < 8; ++q) v[q] = binned[i + 8 * q];
        #pragma unroll
        for (int q = 0; q < 8; ++q)
            r[q] = *(const unsigned*)(xh + (((size_t)(v[q] >> 6)) << 6) + l2 * 2);
        #pragma unroll
        for (int q = 0; q < 8; ++q) {
            int d = (int)(v[q] & 63u);
            unsafeAtomicAdd(&u.s[0][d][l2], bf2f_lo(r[q]));
            unsafeAtomicAdd(&u.s[1][d][l2], bf2f_hi(r[q]));
            if (l2 == 0) atomicAdd(&scnt[d], 1);
        }
    }
    for (; i < ehi; i += 8) {
        unsigned v = binned[i];
        int d = (int)(v & 63u);
        unsigned r = *(const unsigned*)(xh + (((size_t)(v >> 6)) << 6) + l2 * 2);
        unsafeAtomicAdd(&u.s[0][d][l2], bf2f_lo(r));
        unsafeAtomicAdd(&u.s[1][d][l2], bf2f_hi(r));
        if (l2 == 0) atomicAdd(&scnt[d], 1);
    }
    __syncthreads();

    // ---- mean + bf16 pack (reg-stage across the union aliasing) ----
    // thread t: node d = t>>2, feature chunk c = t&3 (16 features).
    // sums[*][d][c*8+j] = features f0+2j (even array) / f0+2j+1 (odd).
    {
        int d = t >> 2, c = t & 3, f0 = c * 16;
        float inv = 1.0f / fmaxf((float)scnt[d], 1.0f);
        float va[8], vb[8];
        #pragma unroll
        for (int j = 0; j < 8; ++j) {
            va[j] = u.s[0][d][c * 8 + j] * inv;
            vb[j] = u.s[1][d][c * 8 + j] * inv;
        }
        __syncthreads();
        #pragma unroll
        for (int j = 0; j < 8; ++j) {
            unsigned pk = (unsigned)f2bf(va[j]) | ((unsigned)f2bf(vb[j]) << 16);
            *(unsigned*)&u.m[d * MLD + f0 + 2 * j] = pk;
        }
    }
    __syncthreads();

    // ---- GEMM: wave w = column quadrant; 4 row-tiles x 4 k-chunks ----
    int w = t >> 6;
    int lane = t & 63;
    int nt = w;
    int n15 = lane & 15;
    int quad = lane >> 4;

    bf16x8 bfrag[4];
    #pragma unroll
    for (int kk = 0; kk < 4; ++kk) {
        const unsigned short* W = (kk < 2) ? wl16 : wr16;
        int kbase = (kk & 1) * 32 + quad * 8;
        #pragma unroll
        for (int j = 0; j < 8; ++j)
            bfrag[kk][j] = (short)W[(kbase + j) * DFEAT + nt * 16 + n15];
    }
    float bias = bl[nt * 16 + n15];

    #pragma unroll
    for (int tt = 0; tt < 4; ++tt) {
        int m = tt * 16 + n15;                       // local node row (A row)
        int grow = n0 + m; if (grow >= N) grow = N - 1;

        bf16x8 a0 = *(const bf16x8*)&u.m[m * MLD + quad * 8];
        bf16x8 a1 = *(const bf16x8*)&u.m[m * MLD + 32 + quad * 8];
        bf16x8 a2 = *(const bf16x8*)(xh + (size_t)grow * DFEAT + quad * 8);
        bf16x8 a3 = *(const bf16x8*)(xh + (size_t)grow * DFEAT + 32 + quad * 8);

        f32x4 c = {0.f, 0.f, 0.f, 0.f};
        c = __builtin_amdgcn_mfma_f32_16x16x32_bf16(a0, bfrag[0], c, 0, 0, 0);
        c = __builtin_amdgcn_mfma_f32_16x16x32_bf16(a1, bfrag[1], c, 0, 0, 0);
        c = __builtin_amdgcn_mfma_f32_16x16x32_bf16(a2, bfrag[2], c, 0, 0, 0);
        c = __builtin_amdgcn_mfma_f32_16x16x32_bf16(a3, bfrag[3], c, 0, 0, 0);

        #pragma unroll
        for (int r = 0; r < 4; ++r) {
            int orow = n0 + tt * 16 + quad * 4 + r;
            if (orow < N)
                out[(size_t)orow * DFEAT + nt * 16 + n15] = c[r] + bias;
        }
    }
}

extern "C" void kernel_launch(void* const* d_in, const int* in_sizes, int n_in,
                              void* d_out, int out_size, void* d_ws, size_t ws_size,
                              hipStream_t stream) {
    const float* x  = (const float*)d_in[0];
    const int*   ei = (const int*)d_in[1];     // [2,E] flat: src then dst
    const float* Wl = (const float*)d_in[2];
    const float* bl = (const float*)d_in[3];
    const float* Wr = (const float*)d_in[4];
    float* out = (float*)d_out;

    const int N = in_sizes[0] / DFEAT;         // 100000
    const int E = in_sizes[1] / 2;             // 1600000
    const int* src = ei;
    const int* dst = ei + E;

    const int nf = (N + 63) >> 6;              // 1563 fine buckets

    // ws: [bcnt 2048][bfill 2048][bbase 2064][binned E][wl16][wr16][xh N*64]
    int* ws = (int*)d_ws;
    int* bcnt  = ws;
    int* bfill = bcnt + NF2;
    int* bbase = bfill + NF2;
    unsigned int* binned = (unsigned int*)(bbase + NF2 + 16);
    unsigned short* wl16 = (unsigned short*)(binned + E);
    unsigned short* wr16 = wl16 + DFEAT * DFEAT;
    unsigned short* xh   = wr16 + DFEAT * DFEAT;

    hipMemsetAsync(bcnt, 0, 2 * NF2 * sizeof(int), stream);

    int nx4 = N * DFEAT / 4;
    int convBlocks = (2048 + nx4 + 255) / 256;
    prep<<<convBlocks + 128, 256, 0, stream>>>(
        x, Wl, Wr, dst, xh, wl16, wr16, bcnt, nx4, convBlocks, E, nf);

    bscan<<<1, 1024, 0, stream>>>(bcnt, bbase, nf);
    binpass<<<256, 1024, 0, stream>>>(src, dst, bbase, bfill, binned, E, nf);

    sage_fused<<<nf, 256, 0, stream>>>(
        xh, binned, bbase, wl16, wr16, bl, out, N);
}

// Round 4
// 170.665 us; speedup vs baseline: 4.2782x; 4.2782x over previous
//
#include <hip/hip_runtime.h>

// GraphSAGEConv: out_i = mean_{j in N(i)} x_j @ W_l + b_l + x_i @ W_r
// N=100000, E=1600000, D_in=D_out=64.
//
// 3 dispatches (no scan, no grid barrier):
//   memset:   gfill[512] = 0 (2 KB)
//   prep_bin: 512 blocks x 512 thr:
//             - convert x->bf16 xh, Wl/Wr->bf16 (grid-strided)
//             - per-chunk LDS histogram of dst (coarse 256-node buckets)
//             - reserve per-bucket ranges directly in FIXED-CAPACITY bucket
//               regions via one global atomicAdd(&gfill[bu], c) per
//               (block,bucket)  [cap = mean+32sigma -> overflow-proof; hard
//               region-end guard prevents cross-bucket writes regardless]
//             - scatter packed (src<<8)|(dst&255) into binned[bu*cap + off]
//   sage_fused: one 256-thr block per 64 nodes (quarter bucket), round-0
//             proven body + round-1-verified XCD swizzle:
//             - blockIdx swizzled so the 4 quarters of a bucket share
//               blockIdx%8 (same XCD -> binned re-reads are L2 hits)
//             - fine-sort quarter's edges into LDS
//             - per-wave aggregation: 16 nodes/wave, half-wave ushort2
//               gathers of 128B bf16 rows, 8-deep ILP, f32 accumulate
//             - means bf16 in LDS (72-short pitch, bank-safe)
//             - dual-GEMM via mfma_f32_16x16x32_bf16 (K=128 fused)

#define DFEAT 64
#define MAXBUCK 512                  // coarse buckets (256 nodes), N <= 131072
#define SORT_CAP 2048                // LDS edge capacity per 64-node quarter
#define MLD 72                       // means row pitch in shorts (bank-safe)

typedef short bf16x8 __attribute__((ext_vector_type(8)));
typedef float f32x4 __attribute__((ext_vector_type(4)));

static __device__ __forceinline__ unsigned short f2bf(float f) {
    unsigned int u = __float_as_uint(f);
    unsigned int r = (u + 0x7FFFu + ((u >> 16) & 1u)) >> 16;   // RNE
    return (unsigned short)r;
}
static __device__ __forceinline__ float bf2f_lo(unsigned int u) {
    return __uint_as_float(u << 16);
}
static __device__ __forceinline__ float bf2f_hi(unsigned int u) {
    return __uint_as_float(u & 0xFFFF0000u);
}

// convert + histogram + direct fixed-region binning, one kernel.
__launch_bounds__(512)
__global__ void prep_bin(const float* __restrict__ x,
                         const float* __restrict__ Wl,
                         const float* __restrict__ Wr,
                         const int* __restrict__ src,
                         const int* __restrict__ dst,
                         unsigned short* __restrict__ xh,
                         unsigned short* __restrict__ wl16,
                         unsigned short* __restrict__ wr16,
                         int* __restrict__ gfill,
                         unsigned int* __restrict__ binned,
                         int nx4, int E, int nbuck, int cap) {
    __shared__ int hcnt[MAXBUCK];
    __shared__ int hbase[MAXBUCK];
    int b = blockIdx.x, t = threadIdx.x;

    for (int i = t; i < nbuck; i += 512) hcnt[i] = 0;

    // ---- convert (grid-strided over Wl, Wr, x) ----
    int total = 2048 + nx4;
    for (int i = b * 512 + t; i < total; i += 512 * 512) {
        const float* sp; unsigned short* dp; int k;
        if (i < 1024)      { sp = Wl; dp = wl16; k = i; }
        else if (i < 2048) { sp = Wr; dp = wr16; k = i - 1024; }
        else               { sp = x;  dp = xh;   k = i - 2048; }
        float4 v = ((const float4*)sp)[k];
        ushort4 hh;
        hh.x = f2bf(v.x); hh.y = f2bf(v.y); hh.z = f2bf(v.z); hh.w = f2bf(v.w);
        ((ushort4*)dp)[k] = hh;
    }

    // ---- per-chunk LDS histogram of dst ----
    int chunk = (E + 511) / 512;
    int lo = b * chunk;
    int hi = lo + chunk; if (hi > E) hi = E;
    __syncthreads();
    for (int i = lo + t; i < hi; i += 512)
        atomicAdd(&hcnt[((unsigned)dst[i]) >> 8], 1);
    __syncthreads();

    // ---- reserve ranges inside fixed-capacity bucket regions ----
    for (int i = t; i < nbuck; i += 512) {
        int c = hcnt[i];
        hbase[i] = c > 0 ? (i * cap + atomicAdd(&gfill[i], c)) : 0;
        hcnt[i] = 0;
    }
    __syncthreads();

    // ---- scatter packed edges (region-end guarded) ----
    for (int i = lo + t; i < hi; i += 512) {
        int d = dst[i];
        int bu = ((unsigned)d) >> 8;
        int p = hbase[bu] + atomicAdd(&hcnt[bu], 1);
        if (p < (bu + 1) * cap)
            binned[p] = (((unsigned)src[i]) << 8) | ((unsigned)d & 255u);
    }
}

// Fused fine-sort + aggregate + dual-GEMM. One block per 64 nodes.
__launch_bounds__(256)
__global__ void sage_fused(const unsigned short* __restrict__ xh,
                           const unsigned int* __restrict__ binned,
                           const int* __restrict__ gfill,
                           const unsigned short* __restrict__ wl16,
                           const unsigned short* __restrict__ wr16,
                           const float* __restrict__ bl,
                           float* __restrict__ out,
                           int N, int nbuck, int cap) {
    __shared__ int scnt[64];
    __shared__ int sbase[64];
    __shared__ int sfill[64];
    __shared__ int sortbuf[SORT_CAP];
    __shared__ unsigned short means[64 * MLD];   // 9216 B

    int xx = blockIdx.x & 7;
    int kq = blockIdx.x >> 3;
    int cb = xx + ((kq >> 2) << 3);     // coarse bucket (XCD-shared quarters)
    int q  = kq & 3;                    // 64-node quarter
    if (cb >= nbuck) return;
    int n0 = (cb << 8) + (q << 6);
    if (n0 >= N) return;
    int nn = N - n0; if (nn > 64) nn = 64;

    int t = threadIdx.x;
    int w = t >> 6;
    int lane = t & 63;

    // ---- fine histogram (filtered to our quarter) ----
    if (t < 64) { scnt[t] = 0; sfill[t] = 0; }
    __syncthreads();
    int elo = cb * cap;
    int cnt = gfill[cb]; if (cnt > cap) cnt = cap;
    int ehi = elo + cnt;
    for (int i = elo + t; i < ehi; i += 256) {
        unsigned int v = binned[i];
        int dlo = (int)(v & 255u);
        if ((dlo >> 6) == q) atomicAdd(&scnt[dlo & 63], 1);
    }
    __syncthreads();
    // ---- exclusive scan of 64 counters (wave 0, shfl) ----
    if (w == 0) {
        int c = scnt[lane];
        int v = c;
        #pragma unroll
        for (int o = 1; o < 64; o <<= 1) {
            int u = __shfl_up(v, o);
            if (lane >= o) v += u;
        }
        sbase[lane] = v - c;
    }
    __syncthreads();
    // ---- place edges into LDS ----
    for (int i = elo + t; i < ehi; i += 256) {
        unsigned int v = binned[i];
        int dlo = (int)(v & 255u);
        if ((dlo >> 6) == q) {
            int d = dlo & 63;
            int p = sbase[d] + atomicAdd(&sfill[d], 1);
            if (p < SORT_CAP) sortbuf[p] = (int)(v >> 8);
        }
    }
    __syncthreads();

    // ---- aggregation: wave w handles nodes w*16 .. w*16+15 ----
    int half = lane >> 5;
    int l2 = lane & 31;
    for (int m = 0; m < 16; ++m) {
        int d = w * 16 + m;
        if (d >= nn) break;
        int s0 = sbase[d];
        int deg = scnt[d];
        int s1 = s0 + deg; if (s1 > SORT_CAP) s1 = SORT_CAP;

        float2 acc[8];
        #pragma unroll
        for (int u = 0; u < 8; ++u) { acc[u].x = 0.f; acc[u].y = 0.f; }

        for (int base = s0; base < s1; base += 64) {
            int cc = s1 - base; if (cc > 64) cc = 64;
            int myidx = (lane < cc) ? sortbuf[base + lane] : 0;
            int pairs = cc >> 1;
            int s = 0;
            for (; s + 8 <= pairs; s += 8) {
                unsigned int vv[8];
                #pragma unroll
                for (int u = 0; u < 8; ++u) {
                    int id = __shfl(myidx, 2 * (s + u) + half);
                    vv[u] = *(const unsigned int*)(xh + (size_t)id * DFEAT + l2 * 2);
                }
                #pragma unroll
                for (int u = 0; u < 8; ++u) {
                    acc[u].x += bf2f_lo(vv[u]);
                    acc[u].y += bf2f_hi(vv[u]);
                }
            }
            for (; s < pairs; ++s) {
                int id = __shfl(myidx, 2 * s + half);
                unsigned int v = *(const unsigned int*)(xh + (size_t)id * DFEAT + l2 * 2);
                acc[0].x += bf2f_lo(v);
                acc[0].y += bf2f_hi(v);
            }
            if (cc & 1) {
                int id = __shfl(myidx, cc - 1);
                unsigned int v = *(const unsigned int*)(xh + (size_t)id * DFEAT + l2 * 2);
                if (half == 0) {
                    acc[1].x += bf2f_lo(v);
                    acc[1].y += bf2f_hi(v);
                }
            }
        }

        float2 s2;
        s2.x = ((acc[0].x + acc[1].x) + (acc[2].x + acc[3].x))
             + ((acc[4].x + acc[5].x) + (acc[6].x + acc[7].x));
        s2.y = ((acc[0].y + acc[1].y) + (acc[2].y + acc[3].y))
             + ((acc[4].y + acc[5].y) + (acc[6].y + acc[7].y));
        s2.x += __shfl_xor(s2.x, 32);
        s2.y += __shfl_xor(s2.y, 32);

        if (lane < 32) {
            float inv = 1.0f / fmaxf((float)deg, 1.0f);
            unsigned int pk = (unsigned int)f2bf(s2.x * inv)
                            | ((unsigned int)f2bf(s2.y * inv) << 16);
            *(unsigned int*)&means[d * MLD + l2 * 2] = pk;
        }
    }
    __syncthreads();

    // ---- GEMM: wave w = column quadrant; 4 row-tiles x 4 k-chunks ----
    int nt = w;
    int n15 = lane & 15;
    int quad = lane >> 4;

    bf16x8 bfrag[4];
    #pragma unroll
    for (int kk = 0; kk < 4; ++kk) {
        const unsigned short* W = (kk < 2) ? wl16 : wr16;
        int kbase = (kk & 1) * 32 + quad * 8;
        #pragma unroll
        for (int j = 0; j < 8; ++j)
            bfrag[kk][j] = (short)W[(kbase + j) * DFEAT + nt * 16 + n15];
    }
    float bias = bl[nt * 16 + n15];

    #pragma unroll
    for (int tt = 0; tt < 4; ++tt) {
        int m = tt * 16 + n15;                       // local node row (A row)
        int grow = n0 + m; if (grow >= N) grow = N - 1;

        bf16x8 a0 = *(const bf16x8*)&means[m * MLD + quad * 8];
        bf16x8 a1 = *(const bf16x8*)&means[m * MLD + 32 + quad * 8];
        bf16x8 a2 = *(const bf16x8*)(xh + (size_t)grow * DFEAT + quad * 8);
        bf16x8 a3 = *(const bf16x8*)(xh + (size_t)grow * DFEAT + 32 + quad * 8);

        f32x4 c = {0.f, 0.f, 0.f, 0.f};
        c = __builtin_amdgcn_mfma_f32_16x16x32_bf16(a0, bfrag[0], c, 0, 0, 0);
        c = __builtin_amdgcn_mfma_f32_16x16x32_bf16(a1, bfrag[1], c, 0, 0, 0);
        c = __builtin_amdgcn_mfma_f32_16x16x32_bf16(a2, bfrag[2], c, 0, 0, 0);
        c = __builtin_amdgcn_mfma_f32_16x16x32_bf16(a3, bfrag[3], c, 0, 0, 0);

        #pragma unroll
        for (int r = 0; r < 4; ++r) {
            int orow = n0 + tt * 16 + quad * 4 + r;
            if (orow < N)
                out[(size_t)orow * DFEAT + nt * 16 + n15] = c[r] + bias;
        }
    }
}

extern "C" void kernel_launch(void* const* d_in, const int* in_sizes, int n_in,
                              void* d_out, int out_size, void* d_ws, size_t ws_size,
                              hipStream_t stream) {
    const float* x  = (const float*)d_in[0];
    const int*   ei = (const int*)d_in[1];     // [2,E] flat: src then dst
    const float* Wl = (const float*)d_in[2];
    const float* bl = (const float*)d_in[3];
    const float* Wr = (const float*)d_in[4];
    float* out = (float*)d_out;

    const int N = in_sizes[0] / DFEAT;         // 100000
    const int E = in_sizes[1] / 2;             // 1600000
    const int* src = ei;
    const int* dst = ei + E;

    const int nbuck = (N + 255) >> 8;          // 391 coarse buckets

    // Bucket capacity: target mean+32sigma (6144), shrink only if ws is
    // tight.  cap is 64-aligned so every bucket region is 256B-aligned.
    size_t fixedBytes = MAXBUCK * sizeof(int)
                      + 2 * DFEAT * DFEAT * sizeof(short)
                      + (size_t)N * DFEAT * sizeof(short) + 4096;
    size_t avail = (ws_size > fixedBytes) ? (ws_size - fixedBytes) : 0;
    long long capl = (long long)(avail / ((size_t)nbuck * sizeof(int)));
    int cap = (capl > 6144) ? 6144 : (int)capl;
    cap &= ~63;
    if (cap < 64) cap = 64;                    // degenerate-ws guard (no OOB)

    // ws: [gfill 512][binned nbuck*cap][wl16 4096][wr16 4096][xh N*64]
    int* gfill = (int*)d_ws;
    unsigned int* binned = (unsigned int*)(gfill + MAXBUCK);
    unsigned short* wl16 = (unsigned short*)(binned + (size_t)nbuck * cap);
    unsigned short* wr16 = wl16 + DFEAT * DFEAT;
    unsigned short* xh   = wr16 + DFEAT * DFEAT;

    hipMemsetAsync(gfill, 0, MAXBUCK * sizeof(int), stream);

    int nx4 = N * DFEAT / 4;
    prep_bin<<<512, 512, 0, stream>>>(
        x, Wl, Wr, src, dst, xh, wl16, wr16, gfill, binned, nx4, E, nbuck, cap);

    int mg = (nbuck + 7) >> 3;
    sage_fused<<<mg * 32, 256, 0, stream>>>(
        xh, binned, gfill, wl16, wr16, bl, out, N, nbuck, cap);
}

// Round 5
// 169.682 us; speedup vs baseline: 4.3030x; 1.0058x over previous
//
#include <hip/hip_runtime.h>

// GraphSAGEConv: out_i = mean_{j in N(i)} x_j @ W_l + b_l + x_i @ W_r
// N=100000, E=1600000, D_in=D_out=64.
//
// 3 dispatches (no scan kernel, no grid barrier):
//   memset:   gfill[2048] = 0 (8 KB)
//   prep_bin: 512 blocks x 512 thr:
//             - convert x->bf16 xh, Wl/Wr->bf16 (grid-strided)
//             - per-chunk LDS histogram of dst at 64-node (sub-bucket)
//               granularity (1564 counters)
//             - reserve ranges in FIXED-CAPACITY per-quarter sub-regions
//               (cap4 = 1536 = mean+16sigma; coarse region = 4*cap4) via one
//               global atomicAdd(&gfill[sub], c) per (block,sub); hard
//               region-end guard drops writes past a sub-region (stat-impossible)
//             - scatter packed (src<<8)|(dst&255) into
//               binned[cb*cap + q*cap4 + off]
//   sage_fused: one 256-thr block per 64 nodes, reads EXACTLY its own
//             sub-region (no filter, no redundant bucket scan):
//             - blockIdx swizzled so the 4 quarters of a bucket share
//               blockIdx%8 (same XCD -> shared L2 for xh reuse)
//             - single reg-staged pass: <=6 edges/thread -> LDS hist ->
//               wave-0 shfl scan -> place into sortbuf (binned read ONCE)
//             - per-wave aggregation: 16 nodes/wave; per-edge index via
//               uniform-address LDS broadcast read (replaces ds_bpermute);
//               half-wave ushort2 gathers of 128B bf16 rows, 8-deep ILP,
//               f32 accumulate
//             - means bf16 in LDS (72-short pitch, bank-safe)
//             - dual-GEMM via mfma_f32_16x16x32_bf16 (K=128 fused)

#define DFEAT 64
#define MAXBUCK 512                  // coarse buckets (256 nodes), N <= 131072
#define NSUB (MAXBUCK * 4)           // 64-node sub-buckets
#define SORT_CAP 2048                // LDS edge capacity per 64-node block
#define MLD 72                       // means row pitch in shorts (bank-safe)
#define EVMAX 6                      // cap4/256 = 1536/256 reg-stage depth

typedef short bf16x8 __attribute__((ext_vector_type(8)));
typedef float f32x4 __attribute__((ext_vector_type(4)));

static __device__ __forceinline__ unsigned short f2bf(float f) {
    unsigned int u = __float_as_uint(f);
    unsigned int r = (u + 0x7FFFu + ((u >> 16) & 1u)) >> 16;   // RNE
    return (unsigned short)r;
}
static __device__ __forceinline__ float bf2f_lo(unsigned int u) {
    return __uint_as_float(u << 16);
}
static __device__ __forceinline__ float bf2f_hi(unsigned int u) {
    return __uint_as_float(u & 0xFFFF0000u);
}

// convert + sub-bucket histogram + direct fixed-region binning, one kernel.
__launch_bounds__(512)
__global__ void prep_bin(const float* __restrict__ x,
                         const float* __restrict__ Wl,
                         const float* __restrict__ Wr,
                         const int* __restrict__ src,
                         const int* __restrict__ dst,
                         unsigned short* __restrict__ xh,
                         unsigned short* __restrict__ wl16,
                         unsigned short* __restrict__ wr16,
                         int* __restrict__ gfill,
                         unsigned int* __restrict__ binned,
                         int nx4, int E, int nsub, int cap, int cap4) {
    __shared__ int hcnt[NSUB];
    __shared__ int hbase[NSUB];
    int b = blockIdx.x, t = threadIdx.x;

    for (int i = t; i < nsub; i += 512) hcnt[i] = 0;

    // ---- convert (grid-strided over Wl, Wr, x) ----
    int total = 2048 + nx4;
    for (int i = b * 512 + t; i < total; i += 512 * 512) {
        const float* sp; unsigned short* dp; int k;
        if (i < 1024)      { sp = Wl; dp = wl16; k = i; }
        else if (i < 2048) { sp = Wr; dp = wr16; k = i - 1024; }
        else               { sp = x;  dp = xh;   k = i - 2048; }
        float4 v = ((const float4*)sp)[k];
        ushort4 hh;
        hh.x = f2bf(v.x); hh.y = f2bf(v.y); hh.z = f2bf(v.z); hh.w = f2bf(v.w);
        ((ushort4*)dp)[k] = hh;
    }

    // ---- per-chunk LDS histogram of dst (64-node granularity) ----
    int chunk = (E + 511) / 512;
    int lo = b * chunk;
    int hi = lo + chunk; if (hi > E) hi = E;
    __syncthreads();
    for (int i = lo + t; i < hi; i += 512)
        atomicAdd(&hcnt[((unsigned)dst[i]) >> 6], 1);
    __syncthreads();

    // ---- reserve ranges inside fixed-capacity sub-regions ----
    for (int i = t; i < nsub; i += 512) {
        int c = hcnt[i];
        hbase[i] = c > 0 ? ((i >> 2) * cap + (i & 3) * cap4
                            + atomicAdd(&gfill[i], c))
                         : 0;
        hcnt[i] = 0;
    }
    __syncthreads();

    // ---- scatter packed edges (sub-region-end guarded) ----
    for (int i = lo + t; i < hi; i += 512) {
        int d = dst[i];
        int bu = ((unsigned)d) >> 6;
        int p = hbase[bu] + atomicAdd(&hcnt[bu], 1);
        int end = (bu >> 2) * cap + ((bu & 3) + 1) * cap4;
        if (p < end)
            binned[p] = (((unsigned)src[i]) << 8) | ((unsigned)d & 255u);
    }
}

// Fused fine-sort + aggregate + dual-GEMM. One block per 64 nodes.
__launch_bounds__(256)
__global__ void sage_fused(const unsigned short* __restrict__ xh,
                           const unsigned int* __restrict__ binned,
                           const int* __restrict__ gfill,
                           const unsigned short* __restrict__ wl16,
                           const unsigned short* __restrict__ wr16,
                           const float* __restrict__ bl,
                           float* __restrict__ out,
                           int N, int nbuck, int cap, int cap4) {
    __shared__ int scnt[64];
    __shared__ int sbase[64];
    __shared__ int sfill[64];
    __shared__ int sortbuf[SORT_CAP];
    __shared__ unsigned short means[64 * MLD];   // 9216 B

    int xx = blockIdx.x & 7;
    int kq = blockIdx.x >> 3;
    int cb = xx + ((kq >> 2) << 3);     // coarse bucket (XCD-shared quarters)
    int q  = kq & 3;                    // 64-node quarter
    if (cb >= nbuck) return;
    int n0 = (cb << 8) + (q << 6);
    if (n0 >= N) return;
    int nn = N - n0; if (nn > 64) nn = 64;

    int t = threadIdx.x;
    int w = t >> 6;
    int lane = t & 63;

    if (t < 64) { scnt[t] = 0; sfill[t] = 0; }
    __syncthreads();

    // ---- single reg-staged pass over OUR sub-region ----
    int elo = cb * cap + q * cap4;
    int cnt = gfill[cb * 4 + q]; if (cnt > cap4) cnt = cap4;
    int ehi = elo + cnt;

    unsigned int ev[EVMAX];
    #pragma unroll
    for (int k = 0; k < EVMAX; ++k) {
        int i = elo + t + k * 256;
        ev[k] = (i < ehi) ? binned[i] : 0xFFFFFFFFu;   // packed < 2^25, safe
    }
    #pragma unroll
    for (int k = 0; k < EVMAX; ++k)
        if (ev[k] != 0xFFFFFFFFu) atomicAdd(&scnt[ev[k] & 63], 1);
    __syncthreads();

    // ---- exclusive scan of 64 counters (wave 0, shfl) ----
    if (w == 0) {
        int c = scnt[lane];
        int v = c;
        #pragma unroll
        for (int o = 1; o < 64; o <<= 1) {
            int u = __shfl_up(v, o);
            if (lane >= o) v += u;
        }
        sbase[lane] = v - c;
    }
    __syncthreads();

    // ---- place edges into LDS (from registers) ----
    #pragma unroll
    for (int k = 0; k < EVMAX; ++k) {
        if (ev[k] != 0xFFFFFFFFu) {
            int d = (int)(ev[k] & 63u);
            int p = sbase[d] + atomicAdd(&sfill[d], 1);
            if (p < SORT_CAP) sortbuf[p] = (int)(ev[k] >> 8);
        }
    }
    __syncthreads();

    // ---- aggregation: wave w handles nodes w*16 .. w*16+15 ----
    int half = lane >> 5;
    int l2 = lane & 31;
    for (int m = 0; m < 16; ++m) {
        int d = w * 16 + m;
        if (d >= nn) break;
        int s0 = sbase[d];
        int deg = scnt[d];
        int s1 = s0 + deg; if (s1 > SORT_CAP) s1 = SORT_CAP;

        float2 acc[8];
        #pragma unroll
        for (int u = 0; u < 8; ++u) { acc[u].x = 0.f; acc[u].y = 0.f; }

        for (int base = s0; base < s1; base += 64) {
            int cc = s1 - base; if (cc > 64) cc = 64;
            int pairs = cc >> 1;
            int s = 0;
            for (; s + 8 <= pairs; s += 8) {
                unsigned int vv[8];
                #pragma unroll
                for (int u = 0; u < 8; ++u) {
                    int id = sortbuf[base + 2 * (s + u) + half];  // LDS broadcast
                    vv[u] = *(const unsigned int*)(xh + (size_t)id * DFEAT + l2 * 2);
                }
                #pragma unroll
                for (int u = 0; u < 8; ++u) {
                    acc[u].x += bf2f_lo(vv[u]);
                    acc[u].y += bf2f_hi(vv[u]);
                }
            }
            for (; s < pairs; ++s) {
                int id = sortbuf[base + 2 * s + half];
                unsigned int v = *(const unsigned int*)(xh + (size_t)id * DFEAT + l2 * 2);
                acc[0].x += bf2f_lo(v);
                acc[0].y += bf2f_hi(v);
            }
            if (cc & 1) {
                int id = sortbuf[base + cc - 1];
                unsigned int v = *(const unsigned int*)(xh + (size_t)id * DFEAT + l2 * 2);
                if (half == 0) {
                    acc[1].x += bf2f_lo(v);
                    acc[1].y += bf2f_hi(v);
                }
            }
        }

        float2 s2;
        s2.x = ((acc[0].x + acc[1].x) + (acc[2].x + acc[3].x))
             + ((acc[4].x + acc[5].x) + (acc[6].x + acc[7].x));
        s2.y = ((acc[0].y + acc[1].y) + (acc[2].y + acc[3].y))
             + ((acc[4].y + acc[5].y) + (acc[6].y + acc[7].y));
        s2.x += __shfl_xor(s2.x, 32);
        s2.y += __shfl_xor(s2.y, 32);

        if (lane < 32) {
            float inv = 1.0f / fmaxf((float)deg, 1.0f);
            unsigned int pk = (unsigned int)f2bf(s2.x * inv)
                            | ((unsigned int)f2bf(s2.y * inv) << 16);
            *(unsigned int*)&means[d * MLD + l2 * 2] = pk;
        }
    }
    __syncthreads();

    // ---- GEMM: wave w = column quadrant; 4 row-tiles x 4 k-chunks ----
    int nt = w;
    int n15 = lane & 15;
    int quad = lane >> 4;

    bf16x8 bfrag[4];
    #pragma unroll
    for (int kk = 0; kk < 4; ++kk) {
        const unsigned short* W = (kk < 2) ? wl16 : wr16;
        int kbase = (kk & 1) * 32 + quad * 8;
        #pragma unroll
        for (int j = 0; j < 8; ++j)
            bfrag[kk][j] = (short)W[(kbase + j) * DFEAT + nt * 16 + n15];
    }
    float bias = bl[nt * 16 + n15];

    #pragma unroll
    for (int tt = 0; tt < 4; ++tt) {
        int m = tt * 16 + n15;                       // local node row (A row)
        int grow = n0 + m; if (grow >= N) grow = N - 1;

        bf16x8 a0 = *(const bf16x8*)&means[m * MLD + quad * 8];
        bf16x8 a1 = *(const bf16x8*)&means[m * MLD + 32 + quad * 8];
        bf16x8 a2 = *(const bf16x8*)(xh + (size_t)grow * DFEAT + quad * 8);
        bf16x8 a3 = *(const bf16x8*)(xh + (size_t)grow * DFEAT + 32 + quad * 8);

        f32x4 c = {0.f, 0.f, 0.f, 0.f};
        c = __builtin_amdgcn_mfma_f32_16x16x32_bf16(a0, bfrag[0], c, 0, 0, 0);
        c = __builtin_amdgcn_mfma_f32_16x16x32_bf16(a1, bfrag[1], c, 0, 0, 0);
        c = __builtin_amdgcn_mfma_f32_16x16x32_bf16(a2, bfrag[2], c, 0, 0, 0);
        c = __builtin_amdgcn_mfma_f32_16x16x32_bf16(a3, bfrag[3], c, 0, 0, 0);

        #pragma unroll
        for (int r = 0; r < 4; ++r) {
            int orow = n0 + tt * 16 + quad * 4 + r;
            if (orow < N)
                out[(size_t)orow * DFEAT + nt * 16 + n15] = c[r] + bias;
        }
    }
}

extern "C" void kernel_launch(void* const* d_in, const int* in_sizes, int n_in,
                              void* d_out, int out_size, void* d_ws, size_t ws_size,
                              hipStream_t stream) {
    const float* x  = (const float*)d_in[0];
    const int*   ei = (const int*)d_in[1];     // [2,E] flat: src then dst
    const float* Wl = (const float*)d_in[2];
    const float* bl = (const float*)d_in[3];
    const float* Wr = (const float*)d_in[4];
    float* out = (float*)d_out;

    const int N = in_sizes[0] / DFEAT;         // 100000
    const int E = in_sizes[1] / 2;             // 1600000
    const int* src = ei;
    const int* dst = ei + E;

    const int nbuck = (N + 255) >> 8;          // 391 coarse buckets
    const int nsub  = nbuck * 4;               // 1564 sub-buckets

    // Sub-region capacity: target mean+16sigma (1536), shrink only if ws is
    // tight.  cap4 is 64-aligned so every sub-region is 256B-aligned.
    size_t fixedBytes = NSUB * sizeof(int)
                      + 2 * DFEAT * DFEAT * sizeof(short)
                      + (size_t)N * DFEAT * sizeof(short) + 4096;
    size_t avail = (ws_size > fixedBytes) ? (ws_size - fixedBytes) : 0;
    long long c4 = (long long)(avail / ((size_t)nsub * sizeof(int)));
    int cap4 = (c4 > 1536) ? 1536 : (int)c4;
    cap4 &= ~63;
    if (cap4 < 64) cap4 = 64;                  // degenerate-ws guard (no OOB)
    int cap = cap4 * 4;

    // ws: [gfill 2048][binned nbuck*cap][wl16 4096][wr16 4096][xh N*64]
    int* gfill = (int*)d_ws;
    unsigned int* binned = (unsigned int*)(gfill + NSUB);
    unsigned short* wl16 = (unsigned short*)(binned + (size_t)nbuck * cap);
    unsigned short* wr16 = wl16 + DFEAT * DFEAT;
    unsigned short* xh   = wr16 + DFEAT * DFEAT;

    hipMemsetAsync(gfill, 0, NSUB * sizeof(int), stream);

    int nx4 = N * DFEAT / 4;
    prep_bin<<<512, 512, 0, stream>>>(
        x, Wl, Wr, src, dst, xh, wl16, wr16, gfill, binned,
        nx4, E, nsub, cap, cap4);

    int mg = (nbuck + 7) >> 3;
    sage_fused<<<mg * 32, 256, 0, stream>>>(
        xh, binned, gfill, wl16, wr16, bl, out, N, nbuck, cap, cap4);
}

// Round 6
// 165.155 us; speedup vs baseline: 4.4210x; 1.0274x over previous
//
#include <hip/hip_runtime.h>

// GraphSAGEConv: out_i = mean_{j in N(i)} x_j @ W_l + b_l + x_i @ W_r
// N=100000, E=1600000, D_in=D_out=64.
//
// 3 dispatches:
//   memset:   gfill[512] u64 = 0 (4 KB)
//   prep_bin: heterogeneous single dispatch, 512 thr/block:
//             - blocks [0,192): convert x->bf16 xh, Wl/Wr->bf16 (grid-strided)
//             - blocks [192, +447): binning, 3584 edges each, reg-staged
//               single read of dst/src (7 edges/thread):
//                 LDS hist at 64-node sub-bucket granularity (1564 counters)
//                 -> PACKED u64 reservation: one atomicAdd reserves all 4
//                    sub-regions of a coarse bucket (4x16-bit fields;
//                    per-sub totals ~1024 << 65536, no cross-field carry)
//                 -> scatter packed (src<<8)|(dst&255) into
//                    binned[cb*cap + q*cap4 + off], sub-region-end guarded
//             convert stream hides under the atomic/scatter-bound binning.
//   sage_fused: one 256-thr block per 64 nodes, reads EXACTLY its own
//             sub-region (round-5 proven body):
//             - blockIdx swizzled so the 4 quarters of a bucket share
//               blockIdx%8 (same XCD -> shared L2 for xh reuse)
//             - single reg-staged pass: <=6 edges/thread -> LDS hist ->
//               wave-0 shfl scan -> place into sortbuf (binned read ONCE)
//             - per-wave aggregation: 16 nodes/wave; per-edge index via
//               uniform-address LDS broadcast read; half-wave ushort2
//               gathers of 128B bf16 rows, 8-deep ILP, f32 accumulate
//             - means bf16 in LDS (72-short pitch, bank-safe)
//             - dual-GEMM via mfma_f32_16x16x32_bf16 (K=128 fused)

#define DFEAT 64
#define MAXBUCK 512                  // coarse buckets (256 nodes), N <= 131072
#define NSUB (MAXBUCK * 4)           // 64-node sub-buckets
#define SORT_CAP 2048                // LDS edge capacity per 64-node block
#define MLD 72                       // means row pitch in shorts (bank-safe)
#define EVMAX 6                      // cap4/256 = 1536/256 reg-stage depth
#define CONVB 192                    // convert blocks
#define BCHUNK 3584                  // edges per binning block (7 * 512)

typedef short bf16x8 __attribute__((ext_vector_type(8)));
typedef float f32x4 __attribute__((ext_vector_type(4)));

static __device__ __forceinline__ unsigned short f2bf(float f) {
    unsigned int u = __float_as_uint(f);
    unsigned int r = (u + 0x7FFFu + ((u >> 16) & 1u)) >> 16;   // RNE
    return (unsigned short)r;
}
static __device__ __forceinline__ float bf2f_lo(unsigned int u) {
    return __uint_as_float(u << 16);
}
static __device__ __forceinline__ float bf2f_hi(unsigned int u) {
    return __uint_as_float(u & 0xFFFF0000u);
}

// heterogeneous: convert blocks + binning blocks, one dispatch.
__launch_bounds__(512)
__global__ void prep_bin(const float* __restrict__ x,
                         const float* __restrict__ Wl,
                         const float* __restrict__ Wr,
                         const int* __restrict__ src,
                         const int* __restrict__ dst,
                         unsigned short* __restrict__ xh,
                         unsigned short* __restrict__ wl16,
                         unsigned short* __restrict__ wr16,
                         unsigned long long* __restrict__ gfill,
                         unsigned int* __restrict__ binned,
                         int nx4, int E, int nbuck, int cap, int cap4) {
    __shared__ int hcnt[NSUB];
    __shared__ int hbase[NSUB];
    int b = blockIdx.x, t = threadIdx.x;

    // ---- convert blocks ----
    if (b < CONVB) {
        int total = 2048 + nx4;
        for (int i = b * 512 + t; i < total; i += CONVB * 512) {
            const float* sp; unsigned short* dp; int k;
            if (i < 1024)      { sp = Wl; dp = wl16; k = i; }
            else if (i < 2048) { sp = Wr; dp = wr16; k = i - 1024; }
            else               { sp = x;  dp = xh;   k = i - 2048; }
            float4 v = ((const float4*)sp)[k];
            ushort4 hh;
            hh.x = f2bf(v.x); hh.y = f2bf(v.y); hh.z = f2bf(v.z); hh.w = f2bf(v.w);
            ((ushort4*)dp)[k] = hh;
        }
        return;
    }

    // ---- binning blocks ----
    int bb = b - CONVB;
    int lo = bb * BCHUNK;
    int hi = lo + BCHUNK; if (hi > E) hi = E;

    for (int i = t; i < NSUB; i += 512) hcnt[i] = 0;

    // reg-stage this block's edges (dst + src), read once
    unsigned dv[7]; int sv[7];
    #pragma unroll
    for (int k = 0; k < 7; ++k) {
        int i = lo + t + (k << 9);
        bool ok = (i < hi);
        dv[k] = ok ? (unsigned)dst[i] : 0xFFFFFFFFu;
        sv[k] = ok ? src[i] : 0;
    }
    __syncthreads();

    // LDS histogram at sub-bucket granularity
    #pragma unroll
    for (int k = 0; k < 7; ++k)
        if (dv[k] != 0xFFFFFFFFu) atomicAdd(&hcnt[dv[k] >> 6], 1);
    __syncthreads();

    // packed u64 reservation: one atomic per coarse bucket per block
    for (int i = t; i < nbuck; i += 512) {
        int c0 = hcnt[4 * i], c1 = hcnt[4 * i + 1];
        int c2 = hcnt[4 * i + 2], c3 = hcnt[4 * i + 3];
        unsigned long long add =  (unsigned long long)(unsigned)c0
                               | ((unsigned long long)(unsigned)c1 << 16)
                               | ((unsigned long long)(unsigned)c2 << 32)
                               | ((unsigned long long)(unsigned)c3 << 48);
        int base = i * cap;
        if (add) {
            unsigned long long old = atomicAdd(&gfill[i], add);
            hbase[4 * i + 0] = base            + (int)( old        & 0xFFFFu);
            hbase[4 * i + 1] = base +     cap4 + (int)((old >> 16) & 0xFFFFu);
            hbase[4 * i + 2] = base + 2 * cap4 + (int)((old >> 32) & 0xFFFFu);
            hbase[4 * i + 3] = base + 3 * cap4 + (int)((old >> 48) & 0xFFFFu);
        }
        hcnt[4 * i] = 0; hcnt[4 * i + 1] = 0;
        hcnt[4 * i + 2] = 0; hcnt[4 * i + 3] = 0;
    }
    __syncthreads();

    // scatter from registers (sub-region-end guarded)
    #pragma unroll
    for (int k = 0; k < 7; ++k) {
        if (dv[k] != 0xFFFFFFFFu) {
            unsigned d = dv[k];
            int sub = (int)(d >> 6);
            int p = hbase[sub] + atomicAdd(&hcnt[sub], 1);
            int end = (sub >> 2) * cap + ((sub & 3) + 1) * cap4;
            if (p < end)
                binned[p] = (((unsigned)sv[k]) << 8) | (d & 255u);
        }
    }
}

// Fused fine-sort + aggregate + dual-GEMM. One block per 64 nodes.
__launch_bounds__(256)
__global__ void sage_fused(const unsigned short* __restrict__ xh,
                           const unsigned int* __restrict__ binned,
                           const unsigned long long* __restrict__ gfill,
                           const unsigned short* __restrict__ wl16,
                           const unsigned short* __restrict__ wr16,
                           const float* __restrict__ bl,
                           float* __restrict__ out,
                           int N, int nbuck, int cap, int cap4) {
    __shared__ int scnt[64];
    __shared__ int sbase[64];
    __shared__ int sfill[64];
    __shared__ int sortbuf[SORT_CAP];
    __shared__ unsigned short means[64 * MLD];   // 9216 B

    int xx = blockIdx.x & 7;
    int kq = blockIdx.x >> 3;
    int cb = xx + ((kq >> 2) << 3);     // coarse bucket (XCD-shared quarters)
    int q  = kq & 3;                    // 64-node quarter
    if (cb >= nbuck) return;
    int n0 = (cb << 8) + (q << 6);
    if (n0 >= N) return;
    int nn = N - n0; if (nn > 64) nn = 64;

    int t = threadIdx.x;
    int w = t >> 6;
    int lane = t & 63;

    if (t < 64) { scnt[t] = 0; sfill[t] = 0; }
    __syncthreads();

    // ---- single reg-staged pass over OUR sub-region ----
    int elo = cb * cap + q * cap4;
    int cnt = (int)((gfill[cb] >> (16 * q)) & 0xFFFFull);
    if (cnt > cap4) cnt = cap4;
    int ehi = elo + cnt;

    unsigned int ev[EVMAX];
    #pragma unroll
    for (int k = 0; k < EVMAX; ++k) {
        int i = elo + t + k * 256;
        ev[k] = (i < ehi) ? binned[i] : 0xFFFFFFFFu;   // packed < 2^25, safe
    }
    #pragma unroll
    for (int k = 0; k < EVMAX; ++k)
        if (ev[k] != 0xFFFFFFFFu) atomicAdd(&scnt[ev[k] & 63], 1);
    __syncthreads();

    // ---- exclusive scan of 64 counters (wave 0, shfl) ----
    if (w == 0) {
        int c = scnt[lane];
        int v = c;
        #pragma unroll
        for (int o = 1; o < 64; o <<= 1) {
            int u = __shfl_up(v, o);
            if (lane >= o) v += u;
        }
        sbase[lane] = v - c;
    }
    __syncthreads();

    // ---- place edges into LDS (from registers) ----
    #pragma unroll
    for (int k = 0; k < EVMAX; ++k) {
        if (ev[k] != 0xFFFFFFFFu) {
            int d = (int)(ev[k] & 63u);
            int p = sbase[d] + atomicAdd(&sfill[d], 1);
            if (p < SORT_CAP) sortbuf[p] = (int)(ev[k] >> 8);
        }
    }
    __syncthreads();

    // ---- aggregation: wave w handles nodes w*16 .. w*16+15 ----
    int half = lane >> 5;
    int l2 = lane & 31;
    for (int m = 0; m < 16; ++m) {
        int d = w * 16 + m;
        if (d >= nn) break;
        int s0 = sbase[d];
        int deg = scnt[d];
        int s1 = s0 + deg; if (s1 > SORT_CAP) s1 = SORT_CAP;

        float2 acc[8];
        #pragma unroll
        for (int u = 0; u < 8; ++u) { acc[u].x = 0.f; acc[u].y = 0.f; }

        for (int base = s0; base < s1; base += 64) {
            int cc = s1 - base; if (cc > 64) cc = 64;
            int pairs = cc >> 1;
            int s = 0;
            for (; s + 8 <= pairs; s += 8) {
                unsigned int vv[8];
                #pragma unroll
                for (int u = 0; u < 8; ++u) {
                    int id = sortbuf[base + 2 * (s + u) + half];  // LDS broadcast
                    vv[u] = *(const unsigned int*)(xh + (size_t)id * DFEAT + l2 * 2);
                }
                #pragma unroll
                for (int u = 0; u < 8; ++u) {
                    acc[u].x += bf2f_lo(vv[u]);
                    acc[u].y += bf2f_hi(vv[u]);
                }
            }
            for (; s < pairs; ++s) {
                int id = sortbuf[base + 2 * s + half];
                unsigned int v = *(const unsigned int*)(xh + (size_t)id * DFEAT + l2 * 2);
                acc[0].x += bf2f_lo(v);
                acc[0].y += bf2f_hi(v);
            }
            if (cc & 1) {
                int id = sortbuf[base + cc - 1];
                unsigned int v = *(const unsigned int*)(xh + (size_t)id * DFEAT + l2 * 2);
                if (half == 0) {
                    acc[1].x += bf2f_lo(v);
                    acc[1].y += bf2f_hi(v);
                }
            }
        }

        float2 s2;
        s2.x = ((acc[0].x + acc[1].x) + (acc[2].x + acc[3].x))
             + ((acc[4].x + acc[5].x) + (acc[6].x + acc[7].x));
        s2.y = ((acc[0].y + acc[1].y) + (acc[2].y + acc[3].y))
             + ((acc[4].y + acc[5].y) + (acc[6].y + acc[7].y));
        s2.x += __shfl_xor(s2.x, 32);
        s2.y += __shfl_xor(s2.y, 32);

        if (lane < 32) {
            float inv = 1.0f / fmaxf((float)deg, 1.0f);
            unsigned int pk = (unsigned int)f2bf(s2.x * inv)
                            | ((unsigned int)f2bf(s2.y * inv) << 16);
            *(unsigned int*)&means[d * MLD + l2 * 2] = pk;
        }
    }
    __syncthreads();

    // ---- GEMM: wave w = column quadrant; 4 row-tiles x 4 k-chunks ----
    int nt = w;
    int n15 = lane & 15;
    int quad = lane >> 4;

    bf16x8 bfrag[4];
    #pragma unroll
    for (int kk = 0; kk < 4; ++kk) {
        const unsigned short* W = (kk < 2) ? wl16 : wr16;
        int kbase = (kk & 1) * 32 + quad * 8;
        #pragma unroll
        for (int j = 0; j < 8; ++j)
            bfrag[kk][j] = (short)W[(kbase + j) * DFEAT + nt * 16 + n15];
    }
    float bias = bl[nt * 16 + n15];

    #pragma unroll
    for (int tt = 0; tt < 4; ++tt) {
        int m = tt * 16 + n15;                       // local node row (A row)
        int grow = n0 + m; if (grow >= N) grow = N - 1;

        bf16x8 a0 = *(const bf16x8*)&means[m * MLD + quad * 8];
        bf16x8 a1 = *(const bf16x8*)&means[m * MLD + 32 + quad * 8];
        bf16x8 a2 = *(const bf16x8*)(xh + (size_t)grow * DFEAT + quad * 8);
        bf16x8 a3 = *(const bf16x8*)(xh + (size_t)grow * DFEAT + 32 + quad * 8);

        f32x4 c = {0.f, 0.f, 0.f, 0.f};
        c = __builtin_amdgcn_mfma_f32_16x16x32_bf16(a0, bfrag[0], c, 0, 0, 0);
        c = __builtin_amdgcn_mfma_f32_16x16x32_bf16(a1, bfrag[1], c, 0, 0, 0);
        c = __builtin_amdgcn_mfma_f32_16x16x32_bf16(a2, bfrag[2], c, 0, 0, 0);
        c = __builtin_amdgcn_mfma_f32_16x16x32_bf16(a3, bfrag[3], c, 0, 0, 0);

        #pragma unroll
        for (int r = 0; r < 4; ++r) {
            int orow = n0 + tt * 16 + quad * 4 + r;
            if (orow < N)
                out[(size_t)orow * DFEAT + nt * 16 + n15] = c[r] + bias;
        }
    }
}

extern "C" void kernel_launch(void* const* d_in, const int* in_sizes, int n_in,
                              void* d_out, int out_size, void* d_ws, size_t ws_size,
                              hipStream_t stream) {
    const float* x  = (const float*)d_in[0];
    const int*   ei = (const int*)d_in[1];     // [2,E] flat: src then dst
    const float* Wl = (const float*)d_in[2];
    const float* bl = (const float*)d_in[3];
    const float* Wr = (const float*)d_in[4];
    float* out = (float*)d_out;

    const int N = in_sizes[0] / DFEAT;         // 100000
    const int E = in_sizes[1] / 2;             // 1600000
    const int* src = ei;
    const int* dst = ei + E;

    const int nbuck = (N + 255) >> 8;          // 391 coarse buckets
    const int nsub  = nbuck * 4;               // 1564 sub-buckets

    // Sub-region capacity: target mean+16sigma (1536), shrink only if ws is
    // tight.  cap4 is 64-aligned so every sub-region is 256B-aligned.
    size_t fixedBytes = MAXBUCK * sizeof(unsigned long long)
                      + 2 * DFEAT * DFEAT * sizeof(short)
                      + (size_t)N * DFEAT * sizeof(short) + 4096;
    size_t avail = (ws_size > fixedBytes) ? (ws_size - fixedBytes) : 0;
    long long c4 = (long long)(avail / ((size_t)nsub * sizeof(int)));
    int cap4 = (c4 > 1536) ? 1536 : (int)c4;
    cap4 &= ~63;
    if (cap4 < 64) cap4 = 64;                  // degenerate-ws guard (no OOB)
    int cap = cap4 * 4;

    // ws: [gfill u64*512][binned nbuck*cap][wl16 4096][wr16 4096][xh N*64]
    unsigned long long* gfill = (unsigned long long*)d_ws;
    unsigned int* binned = (unsigned int*)(gfill + MAXBUCK);
    unsigned short* wl16 = (unsigned short*)(binned + (size_t)nbuck * cap);
    unsigned short* wr16 = wl16 + DFEAT * DFEAT;
    unsigned short* xh   = wr16 + DFEAT * DFEAT;

    hipMemsetAsync(gfill, 0, MAXBUCK * sizeof(unsigned long long), stream);

    int nx4 = N * DFEAT / 4;
    int nbin = (E + BCHUNK - 1) / BCHUNK;      // 447
    prep_bin<<<CONVB + nbin, 512, 0, stream>>>(
        x, Wl, Wr, src, dst, xh, wl16, wr16, gfill, binned,
        nx4, E, nbuck, cap, cap4);

    int mg = (nbuck + 7) >> 3;
    sage_fused<<<mg * 32, 256, 0, stream>>>(
        xh, binned, gfill, wl16, wr16, bl, out, N, nbuck, cap, cap4);
}